// Round 2
// baseline (131.606 us; speedup 1.0000x reference)
//
#include <hip/hip_runtime.h>
#include <hip/hip_bf16.h>
#include <stdint.h>

// Problem constants: B=2, T=2048, D=1024, H=16, W=256, HD=64; M = B*T = 4096.

typedef __attribute__((ext_vector_type(8))) short short8;
typedef __attribute__((ext_vector_type(4))) float f32x4;

#define MFMA16(a, b, c) __builtin_amdgcn_mfma_f32_16x16x32_bf16((a), (b), (c), 0, 0, 0)

static __device__ __forceinline__ void gl_lds16(const void* g, void* l) {
  __builtin_amdgcn_global_load_lds(
      (const __attribute__((address_space(1))) unsigned int*)g,
      (__attribute__((address_space(3))) unsigned int*)l, 16, 0, 0);
}

// ---------------------------------------------------------------- convert all
__global__ void cvt_all(const float* __restrict__ x, const float* __restrict__ wqkv,
                        const float* __restrict__ wo, __hip_bfloat16* __restrict__ xb,
                        __hip_bfloat16* __restrict__ wqkvb,
                        __hip_bfloat16* __restrict__ wob) {
  const int N0 = 524288, N1 = 393216, N2 = 131072;  // granules of 8 floats
  int i = blockIdx.x * blockDim.x + threadIdx.x;
  const int stride = gridDim.x * blockDim.x;
  for (; i < N0 + N1 + N2; i += stride) {
    const float* in;
    __hip_bfloat16* out;
    int gidx;
    if (i < N0) { in = x; out = xb; gidx = i; }
    else if (i < N0 + N1) { in = wqkv; out = wqkvb; gidx = i - N0; }
    else { in = wo; out = wob; gidx = i - N0 - N1; }
    const float4* p = (const float4*)in + (size_t)gidx * 2;
    float4 v0 = p[0], v1 = p[1];
    union { short8 s; __hip_bfloat16 h[8]; } u;
    u.h[0] = __float2bfloat16(v0.x); u.h[1] = __float2bfloat16(v0.y);
    u.h[2] = __float2bfloat16(v0.z); u.h[3] = __float2bfloat16(v0.w);
    u.h[4] = __float2bfloat16(v1.x); u.h[5] = __float2bfloat16(v1.y);
    u.h[6] = __float2bfloat16(v1.z); u.h[7] = __float2bfloat16(v1.w);
    ((short8*)out)[gidx] = u.s;
  }
}

// ---------------------------------------------------------------- 256x256 GEMM
// C[m][n] = sum_k A[m][k]*Bm[n][k] + bias[n].  BK=32, 8 waves (2Mx4N),
// 4-deep circular LDS pipeline, counted vmcnt, K-granule-major LDS layout
// (conflict-free ds_read_b128), setprio around MFMA cluster.
// MODE 0: QKV scatter epilogue.  MODE 1: fp32 out (N must be 1024).
template <int MODE>
__global__ __launch_bounds__(512) void gemm256(
    const __hip_bfloat16* __restrict__ A, const __hip_bfloat16* __restrict__ Bm,
    const float* __restrict__ bias, float* __restrict__ outF,
    __hip_bfloat16* __restrict__ qb, __hip_bfloat16* __restrict__ kb,
    __hip_bfloat16* __restrict__ vt, const int K, const int nbn) {
  __shared__ alignas(128) char smem[131072];  // 4 bufs x (A 16KB + B 16KB)
  const int tid = threadIdx.x;
  const int lane = tid & 63, w = tid >> 6;
  const int wm = w >> 2, wn = w & 3;
  const int r = lane & 15, g = lane >> 4;

  // XCD-aware swizzle (gridDim.x % 8 == 0 in all our launches)
  const int cpx = gridDim.x >> 3;
  const int swz = (blockIdx.x & 7) * cpx + (blockIdx.x >> 3);
  const int bm = swz / nbn, bn = swz % nbn;

  const int NT = K >> 5;  // 32-wide K tiles

  // staging: granule G = round*512 + tid; row = G&255, ks = G>>8
  const int G0 = tid, G1 = tid + 512;
  const int rA0 = G0 & 255, kA0 = G0 >> 8;
  const int rA1 = G1 & 255, kA1 = G1 >> 8;
  const __hip_bfloat16* sA0 = A + (size_t)(bm * 256 + rA0) * K + kA0 * 8;
  const __hip_bfloat16* sA1 = A + (size_t)(bm * 256 + rA1) * K + kA1 * 8;
  const __hip_bfloat16* sB0 = Bm + (size_t)(bn * 256 + rA0) * K + kA0 * 8;
  const __hip_bfloat16* sB1 = Bm + (size_t)(bn * 256 + rA1) * K + kA1 * 8;

  auto stage = [&](int tt) {
    const int bo = (tt & 3) * 32768;
    gl_lds16(sA0 + tt * 32, smem + bo + G0 * 16);
    gl_lds16(sA1 + tt * 32, smem + bo + G1 * 16);
    gl_lds16(sB0 + tt * 32, smem + bo + 16384 + G0 * 16);
    gl_lds16(sB1 + tt * 32, smem + bo + 16384 + G1 * 16);
  };

  const int offA = g * 4096 + (wm * 128 + r) * 16;          // + i*256
  const int offB = 16384 + g * 4096 + (wn * 64 + r) * 16;   // + j*256

  f32x4 acc[8][4] = {};

  auto body = [&](int t) {
    __builtin_amdgcn_s_barrier();
    asm volatile("" ::: "memory");
    __builtin_amdgcn_sched_barrier(0);
    if (t + 3 < NT) stage(t + 3);
    const char* cb = smem + (t & 3) * 32768;
    short8 af[8], bf[4];
#pragma unroll
    for (int i = 0; i < 8; ++i) af[i] = *(const short8*)(cb + offA + i * 256);
#pragma unroll
    for (int j = 0; j < 4; ++j) bf[j] = *(const short8*)(cb + offB + j * 256);
    asm volatile("s_waitcnt lgkmcnt(0)" ::: "memory");
    __builtin_amdgcn_sched_barrier(0);
    __builtin_amdgcn_s_setprio(1);
#pragma unroll
    for (int i = 0; i < 8; ++i)
#pragma unroll
      for (int j = 0; j < 4; ++j) acc[i][j] = MFMA16(af[i], bf[j], acc[i][j]);
    __builtin_amdgcn_s_setprio(0);
  };

  stage(0); stage(1); stage(2);
#pragma unroll 1
  for (int t = 0; t < NT - 3; ++t) {
    asm volatile("s_waitcnt vmcnt(8)" ::: "memory");  // tile t landed (mine)
    body(t);
  }
  asm volatile("s_waitcnt vmcnt(8)" ::: "memory");
  body(NT - 3);
  asm volatile("s_waitcnt vmcnt(4)" ::: "memory");
  body(NT - 2);
  asm volatile("s_waitcnt vmcnt(0)" ::: "memory");
  body(NT - 1);

  // epilogue
  float bjv[4];
  const int nb = bn * 256 + wn * 64;
#pragma unroll
  for (int j = 0; j < 4; ++j) bjv[j] = bias[nb + j * 16 + r];
#pragma unroll
  for (int i = 0; i < 8; ++i) {
    const int m0 = bm * 256 + wm * 128 + i * 16 + g * 4;
#pragma unroll
    for (int j = 0; j < 4; ++j) {
      const int nn = nb + j * 16 + r;
      if (MODE == 1) {
#pragma unroll
        for (int q = 0; q < 4; ++q)
          outF[(size_t)(m0 + q) * 1024 + nn] = acc[i][j][q] + bjv[j];
      } else {
        const int c = nn >> 10, h = (nn >> 6) & 15, hd = nn & 63;
        const int b_ = m0 >> 11, t0 = m0 & 2047;
        const size_t hb = (size_t)(b_ * 16 + h);
        if (c == 0) {
#pragma unroll
          for (int q = 0; q < 4; ++q)
            qb[(hb * 2048 + t0 + q) * 64 + hd] =
                __float2bfloat16((acc[i][j][q] + bjv[j]) * 0.125f);
        } else if (c == 1) {
#pragma unroll
          for (int q = 0; q < 4; ++q)
            kb[(hb * 2048 + t0 + q) * 64 + hd] =
                __float2bfloat16(acc[i][j][q] + bjv[j]);
        } else {
          union { uint2 u; __hip_bfloat16 hh[4]; } pk;
#pragma unroll
          for (int q = 0; q < 4; ++q)
            pk.hh[q] = __float2bfloat16(acc[i][j][q] + bjv[j]);
          *(uint2*)&vt[(hb * 64 + hd) * 2048 + t0] = pk.u;
        }
      }
    }
  }
}

// ---------------------------------------------------------------- 128x128 GEMM
// (kept for the out-projection: M=4096, N=1024 -> 256 blocks, proven correct)
__global__ __launch_bounds__(256) void gemm_bt_out(
    const __hip_bfloat16* __restrict__ A, const __hip_bfloat16* __restrict__ Bm,
    const float* __restrict__ bias, float* __restrict__ outF, int K, int nbn) {
  __shared__ alignas(16) __hip_bfloat16 As[128 * 32];
  __shared__ alignas(16) __hip_bfloat16 Bs[128 * 32];
  const int bm = blockIdx.x / nbn, bn = blockIdx.x % nbn;
  const int tid = threadIdx.x;
  const int lane = tid & 63, w = tid >> 6;
  const int wr = w >> 1, wc = w & 1;
  const int r = lane & 15, g = lane >> 4;

  f32x4 acc[4][4] = {};

  const int c0 = tid, c1 = tid + 256;
  const __hip_bfloat16* a0 = A + (size_t)(bm * 128 + (c0 >> 2)) * K + (c0 & 3) * 8;
  const __hip_bfloat16* a1 = A + (size_t)(bm * 128 + (c1 >> 2)) * K + (c1 & 3) * 8;
  const __hip_bfloat16* b0 = Bm + (size_t)(bn * 128 + (c0 >> 2)) * K + (c0 & 3) * 8;
  const __hip_bfloat16* b1 = Bm + (size_t)(bn * 128 + (c1 >> 2)) * K + (c1 & 3) * 8;
  __hip_bfloat16* la0 = &As[c0 * 8];
  __hip_bfloat16* la1 = &As[c1 * 8];
  __hip_bfloat16* lb0 = &Bs[c0 * 8];
  __hip_bfloat16* lb1 = &Bs[c1 * 8];

  for (int k0 = 0; k0 < K; k0 += 32) {
    gl_lds16(a0 + k0, la0);
    gl_lds16(a1 + k0, la1);
    gl_lds16(b0 + k0, lb0);
    gl_lds16(b1 + k0, lb1);
    __syncthreads();
    short8 af[4], bf[4];
#pragma unroll
    for (int i = 0; i < 4; ++i)
      af[i] = *(const short8*)&As[(wr * 64 + i * 16 + r) * 32 + g * 8];
#pragma unroll
    for (int j = 0; j < 4; ++j)
      bf[j] = *(const short8*)&Bs[(wc * 64 + j * 16 + r) * 32 + g * 8];
#pragma unroll
    for (int i = 0; i < 4; ++i)
#pragma unroll
      for (int j = 0; j < 4; ++j) acc[i][j] = MFMA16(af[i], bf[j], acc[i][j]);
    __syncthreads();
  }

#pragma unroll
  for (int i = 0; i < 4; ++i) {
    const int mbase = bm * 128 + wr * 64 + i * 16 + g * 4;
#pragma unroll
    for (int j = 0; j < 4; ++j) {
      const int nn = bn * 128 + wc * 64 + j * 16 + r;
      const float bv = bias[nn];
#pragma unroll
      for (int q = 0; q < 4; ++q)
        outF[(size_t)(mbase + q) * 1024 + nn] = acc[i][j][q] + bv;
    }
  }
}

// ---------------------------------------------------------------- attention
__global__ __launch_bounds__(256) void attn_local(
    const __hip_bfloat16* __restrict__ qb, const __hip_bfloat16* __restrict__ kb,
    const __hip_bfloat16* __restrict__ vt, __hip_bfloat16* __restrict__ yb) {
  __shared__ alignas(16) __hip_bfloat16 plds[4][16 * 32];
  const int bh = blockIdx.x >> 5;  // b*16 + h
  const int qt = blockIdx.x & 31;
  const int w = threadIdx.x >> 6, lane = threadIdx.x & 63;
  const int r = lane & 15, g = lane >> 4;
  const int qa = qt * 64 + w * 16;

  const __hip_bfloat16* qp = qb + (size_t)bh * 2048 * 64;
  const __hip_bfloat16* kp = kb + (size_t)bh * 2048 * 64;
  const __hip_bfloat16* vp = vt + (size_t)bh * 64 * 2048;

  const short8 qf0 = *(const short8*)&qp[(qa + r) * 64 + g * 8];
  const short8 qf1 = *(const short8*)&qp[(qa + r) * 64 + g * 8 + 32];

  f32x4 acc[4] = {};
  float mrow[4] = {-1e30f, -1e30f, -1e30f, -1e30f};
  float lrow[4] = {0.f, 0.f, 0.f, 0.f};

  const int jmin = qa > 255 ? qa - 255 : 0;
  const int kb_lo = jmin >> 5;
  const int kb_hi = (qa + 15) >> 5;

  for (int kbi = kb_lo; kbi <= kb_hi; ++kbi) {
    const int kbase = kbi << 5;
    f32x4 s[2] = {};
#pragma unroll
    for (int f = 0; f < 2; ++f) {
      short8 kf0 = *(const short8*)&kp[(kbase + f * 16 + r) * 64 + g * 8];
      short8 kf1 = *(const short8*)&kp[(kbase + f * 16 + r) * 64 + g * 8 + 32];
      s[f] = MFMA16(qf0, kf0, s[f]);
      s[f] = MFMA16(qf1, kf1, s[f]);
    }
    bool valid[2][4];
    float sv[2][4];
#pragma unroll
    for (int f = 0; f < 2; ++f)
#pragma unroll
      for (int q = 0; q < 4; ++q) {
        const int i_ = qa + g * 4 + q;
        const int j_ = kbase + f * 16 + r;
        valid[f][q] = (j_ <= i_) && (j_ + 255 >= i_);
        sv[f][q] = valid[f][q] ? s[f][q] : -1e30f;
      }
    float rm[4];
#pragma unroll
    for (int q = 0; q < 4; ++q) rm[q] = fmaxf(sv[0][q], sv[1][q]);
#pragma unroll
    for (int d = 1; d < 16; d <<= 1)
#pragma unroll
      for (int q = 0; q < 4; ++q) rm[q] = fmaxf(rm[q], __shfl_xor(rm[q], d));
    float p[2][4], rs[4];
#pragma unroll
    for (int q = 0; q < 4; ++q) {
      const float mnew = fmaxf(mrow[q], rm[q]);
      const float fac = __expf(mrow[q] - mnew);
      mrow[q] = mnew;
      lrow[q] *= fac;
#pragma unroll
      for (int hdb = 0; hdb < 4; ++hdb) acc[hdb][q] *= fac;
      p[0][q] = valid[0][q] ? __expf(sv[0][q] - mnew) : 0.f;
      p[1][q] = valid[1][q] ? __expf(sv[1][q] - mnew) : 0.f;
      rs[q] = p[0][q] + p[1][q];
    }
#pragma unroll
    for (int d = 1; d < 16; d <<= 1)
#pragma unroll
      for (int q = 0; q < 4; ++q) rs[q] += __shfl_xor(rs[q], d);
#pragma unroll
    for (int q = 0; q < 4; ++q) lrow[q] += rs[q];
#pragma unroll
    for (int f = 0; f < 2; ++f)
#pragma unroll
      for (int q = 0; q < 4; ++q)
        plds[w][(g * 4 + q) * 32 + f * 16 + r] = __float2bfloat16(p[f][q]);
    asm volatile("s_waitcnt lgkmcnt(0)" ::: "memory");
    __builtin_amdgcn_sched_barrier(0);
    const short8 pa = *(const short8*)&plds[w][r * 32 + g * 8];
#pragma unroll
    for (int hdb = 0; hdb < 4; ++hdb) {
      short8 vf = *(const short8*)&vp[(size_t)(hdb * 16 + r) * 2048 + kbase + g * 8];
      acc[hdb] = MFMA16(pa, vf, acc[hdb]);
    }
  }

  const int b_ = bh >> 4, h = bh & 15;
#pragma unroll
  for (int hdb = 0; hdb < 4; ++hdb)
#pragma unroll
    for (int q = 0; q < 4; ++q) {
      const int i_ = qa + g * 4 + q;
      yb[(size_t)(b_ * 2048 + i_) * 1024 + h * 64 + hdb * 16 + r] =
          __float2bfloat16(acc[hdb][q] / lrow[q]);
    }
}

// ---------------------------------------------------------------- launch
extern "C" void kernel_launch(void* const* d_in, const int* in_sizes, int n_in,
                              void* d_out, int out_size, void* d_ws,
                              size_t ws_size, hipStream_t stream) {
  const float* x = (const float*)d_in[0];
  const float* Wqkv = (const float*)d_in[1];
  const float* bqkv = (const float*)d_in[2];
  const float* Wo = (const float*)d_in[3];
  const float* bo = (const float*)d_in[4];
  float* out = (float*)d_out;

  char* ws = (char*)d_ws;
  __hip_bfloat16* xb = (__hip_bfloat16*)(ws + 0);                    // 8 MB
  __hip_bfloat16* wqkvb = (__hip_bfloat16*)(ws + 8388608);           // 6 MB
  __hip_bfloat16* wob = (__hip_bfloat16*)(ws + 14680064);            // 2 MB
  __hip_bfloat16* qb = (__hip_bfloat16*)(ws + 16777216);             // 8 MB
  __hip_bfloat16* kb = (__hip_bfloat16*)(ws + 25165824);             // 8 MB
  __hip_bfloat16* vt = (__hip_bfloat16*)(ws + 33554432);             // 8 MB
  __hip_bfloat16* yb = (__hip_bfloat16*)(ws + 41943040);             // 8 MB

  cvt_all<<<2048, 256, 0, stream>>>(x, Wqkv, Wo, xb, wqkvb, wob);

  // QKV: M=4096, N=3072, K=1024 -> 16x12 = 192 blocks of 256x256
  gemm256<0><<<192, 512, 0, stream>>>(xb, wqkvb, bqkv, nullptr, qb, kb, vt,
                                      1024, 12);
  // attention: (B*H) * (T/64) = 32 * 32 blocks
  attn_local<<<1024, 256, 0, stream>>>(qb, kb, vt, yb);
  // out: M=4096, N=1024, K=1024 -> 32x8 = 256 blocks of 128x128
  gemm_bt_out<<<256, 256, 0, stream>>>(yb, wob, bo, out, 1024, 8);
}

// Round 3
// 116.617 us; speedup vs baseline: 1.1285x; 1.1285x over previous
//
#include <hip/hip_runtime.h>
#include <hip/hip_bf16.h>
#include <stdint.h>

// Problem constants: B=2, T=2048, D=1024, H=16, W=256, HD=64; M = B*T = 4096.

typedef __attribute__((ext_vector_type(8))) short short8;
typedef __attribute__((ext_vector_type(4))) float f32x4;

#define MFMA16(a, b, c) __builtin_amdgcn_mfma_f32_16x16x32_bf16((a), (b), (c), 0, 0, 0)

static __device__ __forceinline__ void gl_lds16(const void* g, void* l) {
  __builtin_amdgcn_global_load_lds(
      (const __attribute__((address_space(1))) unsigned int*)g,
      (__attribute__((address_space(3))) unsigned int*)l, 16, 0, 0);
}

#define LGKM0 do { asm volatile("s_waitcnt lgkmcnt(0)" ::: "memory"); \
                   __builtin_amdgcn_sched_barrier(0); } while (0)
#define BARM do { asm volatile("" ::: "memory"); \
                  __builtin_amdgcn_s_barrier(); \
                  asm volatile("" ::: "memory"); } while (0)

// ---------------------------------------------------------------- convert all
__global__ void cvt_all(const float* __restrict__ x, const float* __restrict__ wqkv,
                        const float* __restrict__ wo, __hip_bfloat16* __restrict__ xb,
                        __hip_bfloat16* __restrict__ wqkvb,
                        __hip_bfloat16* __restrict__ wob) {
  const int N0 = 524288, N1 = 393216, N2 = 131072;  // granules of 8 floats
  int i = blockIdx.x * blockDim.x + threadIdx.x;
  const int stride = gridDim.x * blockDim.x;
  for (; i < N0 + N1 + N2; i += stride) {
    const float* in;
    __hip_bfloat16* out;
    int gidx;
    if (i < N0) { in = x; out = xb; gidx = i; }
    else if (i < N0 + N1) { in = wqkv; out = wqkvb; gidx = i - N0; }
    else { in = wo; out = wob; gidx = i - N0 - N1; }
    const float4* p = (const float4*)in + (size_t)gidx * 2;
    float4 v0 = p[0], v1 = p[1];
    union { short8 s; __hip_bfloat16 h[8]; } u;
    u.h[0] = __float2bfloat16(v0.x); u.h[1] = __float2bfloat16(v0.y);
    u.h[2] = __float2bfloat16(v0.z); u.h[3] = __float2bfloat16(v0.w);
    u.h[4] = __float2bfloat16(v1.x); u.h[5] = __float2bfloat16(v1.y);
    u.h[6] = __float2bfloat16(v1.z); u.h[7] = __float2bfloat16(v1.w);
    ((short8*)out)[gidx] = u.s;
  }
}

// ---------------------------------------------------------------- 256x256 8-phase GEMM
// C[m][n] = sum_k A[m][k]*Bm[n][k] + bias[n].  BM=BN=256, BK=64, 8 waves (2Mx4N).
// LDS 128KB = 2 bufs x (A 32KB + B 32KB); each matrix tile stored as
// [kq in 2 planes of 16KB][256 rows][64B], swizzled: granule ^= (row>>1)&3.
// Staged via global_load_lds with pre-swizzled global source (linear LDS dest).
// Per K-tile: 4 phases, each = {ds_read subtile | stage half-tile | bar |
// lgkm0 | setprio 16xMFMA | bar}; vmcnt(4) once per tile (2 half-tiles in flight).
// MODE 0: QKV scatter epilogue.  MODE 1: fp32 out (ldC=1024).
template <int MODE>
__global__ __launch_bounds__(512, 2) void gemm256p(
    const __hip_bfloat16* __restrict__ A, const __hip_bfloat16* __restrict__ Bm,
    const float* __restrict__ bias, float* __restrict__ outF,
    __hip_bfloat16* __restrict__ qb, __hip_bfloat16* __restrict__ kb,
    __hip_bfloat16* __restrict__ vt, const int K, const int nbn) {
  __shared__ alignas(128) char smem[131072];
  const int tid = threadIdx.x;
  const int l = tid & 63, w = tid >> 6;
  const int wm = w >> 2, wn = w & 3;
  const int r = l & 15, g = l >> 4;

  // XCD-aware swizzle (gridDim.x % 8 == 0 in all launches)
  const int cpx = gridDim.x >> 3;
  const int swzb = (blockIdx.x & 7) * cpx + (blockIdx.x >> 3);
  const int bm = swzb / nbn, bn = swzb % nbn;

  const int NT = K >> 6;  // 64-wide K tiles

  // ---- staging (write) setup: wave w stages rows w*16..w*16+15 of each half,
  // call c -> kq plane c.  Lane l: row += l>>2, granule (l&3), global granule
  // pre-swizzled: gsw = (l&3) ^ ((l>>3)&3).
  const int gsw = (l & 3) ^ ((l >> 3) & 3);
  const __hip_bfloat16* gA = A + (size_t)(bm * 256 + w * 16 + (l >> 2)) * K + gsw * 8;
  const __hip_bfloat16* gB = Bm + (size_t)(bn * 256 + w * 16 + (l >> 2)) * K + gsw * 8;
  const int ldc0 = w * 1024 + l * 16;           // kq plane 0 dest (+ h*8192)
  const int ldc1 = 16384 + w * 1024 + l * 16;   // kq plane 1 dest

  // ---- ds_read (read) setup: byte = kq*16384 + row*64 + swizzled granule.
  // row = (wm*128|wn*64) + frag*16 + r  ->  (row>>1)&3 == (r>>1)&3.
  const int swr = (g ^ ((r >> 1) & 3)) * 16;
  const int rdA = wm * 8192 + r * 64 + swr;            // + buf + kq*16384 + i*1024
  const int rdB = 32768 + wn * 4096 + r * 64 + swr;    // + buf + kq*16384 + j*1024

#define STAGE_A(t, h)                                                       \
  do {                                                                      \
    char* d_ = smem + (((t) & 1) * 65536) + (h) * 8192;                     \
    const __hip_bfloat16* s_ = gA + (size_t)(h) * 128 * K + (t) * 64;       \
    gl_lds16(s_, d_ + ldc0);                                                \
    gl_lds16(s_ + 32, d_ + ldc1);                                           \
  } while (0)
#define STAGE_B(t, h)                                                       \
  do {                                                                      \
    char* d_ = smem + (((t) & 1) * 65536) + 32768 + (h) * 8192;             \
    const __hip_bfloat16* s_ = gB + (size_t)(h) * 128 * K + (t) * 64;       \
    gl_lds16(s_, d_ + ldc0);                                                \
    gl_lds16(s_ + 32, d_ + ldc1);                                           \
  } while (0)

  f32x4 acc[8][4] = {};
  short8 a0[4][2], a1[4][2], b0[2][2], b1[2][2];

  // prologue: tile0 {A0,A1,B0,B1}, tile1 {A0,A1}  (issue order matters)
  STAGE_A(0, 0); STAGE_A(0, 1); STAGE_B(0, 0); STAGE_B(0, 1);
  if (NT > 1) { STAGE_A(1, 0); STAGE_A(1, 1); }
  asm volatile("s_waitcnt vmcnt(4)" ::: "memory");
  BARM;

#pragma unroll 1
  for (int t = 0; t < NT; ++t) {
    const char* cb = smem + (t & 1) * 65536;
    // ---- ph0: read A[mh0]+B[nh0]; stage B0(t+1); compute Q(0,0)
#pragma unroll
    for (int i = 0; i < 4; ++i) {
      a0[i][0] = *(const short8*)(cb + rdA + i * 1024);
      a0[i][1] = *(const short8*)(cb + 16384 + rdA + i * 1024);
    }
#pragma unroll
    for (int j = 0; j < 2; ++j) {
      b0[j][0] = *(const short8*)(cb + rdB + j * 1024);
      b0[j][1] = *(const short8*)(cb + 16384 + rdB + j * 1024);
    }
    if (t + 1 < NT) STAGE_B(t + 1, 0);
    BARM;
    LGKM0;
    __builtin_amdgcn_s_setprio(1);
#pragma unroll
    for (int i = 0; i < 4; ++i)
#pragma unroll
      for (int j = 0; j < 2; ++j)
        acc[i][j] = MFMA16(a0[i][1], b0[j][1], MFMA16(a0[i][0], b0[j][0], acc[i][j]));
    __builtin_amdgcn_s_setprio(0);
    BARM;
    // ---- ph1: read A[mh1]; stage B1(t+1); compute Q(1,0)
#pragma unroll
    for (int i = 0; i < 4; ++i) {
      a1[i][0] = *(const short8*)(cb + rdA + (i + 4) * 1024);
      a1[i][1] = *(const short8*)(cb + 16384 + rdA + (i + 4) * 1024);
    }
    if (t + 1 < NT) STAGE_B(t + 1, 1);
    BARM;
    LGKM0;
    __builtin_amdgcn_s_setprio(1);
#pragma unroll
    for (int i = 0; i < 4; ++i)
#pragma unroll
      for (int j = 0; j < 2; ++j)
        acc[i + 4][j] = MFMA16(a1[i][1], b0[j][1], MFMA16(a1[i][0], b0[j][0], acc[i + 4][j]));
    __builtin_amdgcn_s_setprio(0);
    BARM;
    // ---- ph2: read B[nh1]; stage A0(t+2); compute Q(1,1)
#pragma unroll
    for (int j = 0; j < 2; ++j) {
      b1[j][0] = *(const short8*)(cb + rdB + (j + 2) * 1024);
      b1[j][1] = *(const short8*)(cb + 16384 + rdB + (j + 2) * 1024);
    }
    if (t + 2 < NT) STAGE_A(t + 2, 0);
    BARM;
    LGKM0;
    __builtin_amdgcn_s_setprio(1);
#pragma unroll
    for (int i = 0; i < 4; ++i)
#pragma unroll
      for (int j = 0; j < 2; ++j)
        acc[i + 4][j + 2] = MFMA16(a1[i][1], b1[j][1], MFMA16(a1[i][0], b1[j][0], acc[i + 4][j + 2]));
    __builtin_amdgcn_s_setprio(0);
    BARM;
    // ---- ph3: no reads; stage A1(t+2); compute Q(0,1)
    if (t + 2 < NT) STAGE_A(t + 2, 1);
    BARM;
    __builtin_amdgcn_s_setprio(1);
#pragma unroll
    for (int i = 0; i < 4; ++i)
#pragma unroll
      for (int j = 0; j < 2; ++j)
        acc[i][j + 2] = MFMA16(a0[i][1], b1[j][1], MFMA16(a0[i][0], b1[j][0], acc[i][j + 2]));
    __builtin_amdgcn_s_setprio(0);
    // tile handoff: next tile's B must be landed before ph0 reads.
    if (t + 2 < NT) {
      asm volatile("s_waitcnt vmcnt(4)" ::: "memory");
    } else if (t + 1 < NT) {
      asm volatile("s_waitcnt vmcnt(0)" ::: "memory");
    }
    BARM;
  }
#undef STAGE_A
#undef STAGE_B

  // ---- epilogue
  float bjv[4];
  const int nb = bn * 256 + wn * 64;
#pragma unroll
  for (int j = 0; j < 4; ++j) bjv[j] = bias[nb + j * 16 + r];
#pragma unroll
  for (int i = 0; i < 8; ++i) {
    const int m0 = bm * 256 + wm * 128 + i * 16 + g * 4;
#pragma unroll
    for (int j = 0; j < 4; ++j) {
      const int nn = nb + j * 16 + r;
      if (MODE == 1) {
#pragma unroll
        for (int q = 0; q < 4; ++q)
          outF[(size_t)(m0 + q) * 1024 + nn] = acc[i][j][q] + bjv[j];
      } else {
        const int c = nn >> 10, h = (nn >> 6) & 15, hd = nn & 63;
        const int b_ = m0 >> 11, t0 = m0 & 2047;
        const size_t hb = (size_t)(b_ * 16 + h);
        if (c == 0) {
#pragma unroll
          for (int q = 0; q < 4; ++q)
            qb[(hb * 2048 + t0 + q) * 64 + hd] =
                __float2bfloat16((acc[i][j][q] + bjv[j]) * 0.125f);
        } else if (c == 1) {
#pragma unroll
          for (int q = 0; q < 4; ++q)
            kb[(hb * 2048 + t0 + q) * 64 + hd] =
                __float2bfloat16(acc[i][j][q] + bjv[j]);
        } else {
          union { uint2 u; __hip_bfloat16 hh[4]; } pk;
#pragma unroll
          for (int q = 0; q < 4; ++q)
            pk.hh[q] = __float2bfloat16(acc[i][j][q] + bjv[j]);
          *(uint2*)&vt[(hb * 64 + hd) * 2048 + t0] = pk.u;
        }
      }
    }
  }
}

// ---------------------------------------------------------------- 128x128 GEMM
// (out-projection: M=4096, N=1024 -> 256 blocks; proven correct/fast enough)
__global__ __launch_bounds__(256) void gemm_bt_out(
    const __hip_bfloat16* __restrict__ A, const __hip_bfloat16* __restrict__ Bm,
    const float* __restrict__ bias, float* __restrict__ outF, int K, int nbn) {
  __shared__ alignas(16) __hip_bfloat16 As[128 * 32];
  __shared__ alignas(16) __hip_bfloat16 Bs[128 * 32];
  const int bm = blockIdx.x / nbn, bn = blockIdx.x % nbn;
  const int tid = threadIdx.x;
  const int lane = tid & 63, w = tid >> 6;
  const int wr = w >> 1, wc = w & 1;
  const int r = lane & 15, g = lane >> 4;

  f32x4 acc[4][4] = {};

  const int c0 = tid, c1 = tid + 256;
  const __hip_bfloat16* a0 = A + (size_t)(bm * 128 + (c0 >> 2)) * K + (c0 & 3) * 8;
  const __hip_bfloat16* a1 = A + (size_t)(bm * 128 + (c1 >> 2)) * K + (c1 & 3) * 8;
  const __hip_bfloat16* b0 = Bm + (size_t)(bn * 128 + (c0 >> 2)) * K + (c0 & 3) * 8;
  const __hip_bfloat16* b1 = Bm + (size_t)(bn * 128 + (c1 >> 2)) * K + (c1 & 3) * 8;
  __hip_bfloat16* la0 = &As[c0 * 8];
  __hip_bfloat16* la1 = &As[c1 * 8];
  __hip_bfloat16* lb0 = &Bs[c0 * 8];
  __hip_bfloat16* lb1 = &Bs[c1 * 8];

  for (int k0 = 0; k0 < K; k0 += 32) {
    gl_lds16(a0 + k0, la0);
    gl_lds16(a1 + k0, la1);
    gl_lds16(b0 + k0, lb0);
    gl_lds16(b1 + k0, lb1);
    __syncthreads();
    short8 af[4], bf[4];
#pragma unroll
    for (int i = 0; i < 4; ++i)
      af[i] = *(const short8*)&As[(wr * 64 + i * 16 + r) * 32 + g * 8];
#pragma unroll
    for (int j = 0; j < 4; ++j)
      bf[j] = *(const short8*)&Bs[(wc * 64 + j * 16 + r) * 32 + g * 8];
#pragma unroll
    for (int i = 0; i < 4; ++i)
#pragma unroll
      for (int j = 0; j < 4; ++j) acc[i][j] = MFMA16(af[i], bf[j], acc[i][j]);
    __syncthreads();
  }

#pragma unroll
  for (int i = 0; i < 4; ++i) {
    const int mbase = bm * 128 + wr * 64 + i * 16 + g * 4;
#pragma unroll
    for (int j = 0; j < 4; ++j) {
      const int nn = bn * 128 + wc * 64 + j * 16 + r;
      const float bv = bias[nn];
#pragma unroll
      for (int q = 0; q < 4; ++q)
        outF[(size_t)(mbase + q) * 1024 + nn] = acc[i][j][q] + bv;
    }
  }
}

// ---------------------------------------------------------------- attention
__global__ __launch_bounds__(256) void attn_local(
    const __hip_bfloat16* __restrict__ qb, const __hip_bfloat16* __restrict__ kb,
    const __hip_bfloat16* __restrict__ vt, __hip_bfloat16* __restrict__ yb) {
  __shared__ alignas(16) __hip_bfloat16 plds[4][16 * 32];
  const int bh = blockIdx.x >> 5;  // b*16 + h
  const int qt = blockIdx.x & 31;
  const int w = threadIdx.x >> 6, lane = threadIdx.x & 63;
  const int r = lane & 15, g = lane >> 4;
  const int qa = qt * 64 + w * 16;

  const __hip_bfloat16* qp = qb + (size_t)bh * 2048 * 64;
  const __hip_bfloat16* kp = kb + (size_t)bh * 2048 * 64;
  const __hip_bfloat16* vp = vt + (size_t)bh * 64 * 2048;

  const short8 qf0 = *(const short8*)&qp[(qa + r) * 64 + g * 8];
  const short8 qf1 = *(const short8*)&qp[(qa + r) * 64 + g * 8 + 32];

  f32x4 acc[4] = {};
  float mrow[4] = {-1e30f, -1e30f, -1e30f, -1e30f};
  float lrow[4] = {0.f, 0.f, 0.f, 0.f};

  const int jmin = qa > 255 ? qa - 255 : 0;
  const int kb_lo = jmin >> 5;
  const int kb_hi = (qa + 15) >> 5;

  for (int kbi = kb_lo; kbi <= kb_hi; ++kbi) {
    const int kbase = kbi << 5;
    f32x4 s[2] = {};
#pragma unroll
    for (int f = 0; f < 2; ++f) {
      short8 kf0 = *(const short8*)&kp[(kbase + f * 16 + r) * 64 + g * 8];
      short8 kf1 = *(const short8*)&kp[(kbase + f * 16 + r) * 64 + g * 8 + 32];
      s[f] = MFMA16(qf0, kf0, s[f]);
      s[f] = MFMA16(qf1, kf1, s[f]);
    }
    bool valid[2][4];
    float sv[2][4];
#pragma unroll
    for (int f = 0; f < 2; ++f)
#pragma unroll
      for (int q = 0; q < 4; ++q) {
        const int i_ = qa + g * 4 + q;
        const int j_ = kbase + f * 16 + r;
        valid[f][q] = (j_ <= i_) && (j_ + 255 >= i_);
        sv[f][q] = valid[f][q] ? s[f][q] : -1e30f;
      }
    float rm[4];
#pragma unroll
    for (int q = 0; q < 4; ++q) rm[q] = fmaxf(sv[0][q], sv[1][q]);
#pragma unroll
    for (int d = 1; d < 16; d <<= 1)
#pragma unroll
      for (int q = 0; q < 4; ++q) rm[q] = fmaxf(rm[q], __shfl_xor(rm[q], d));
    float p[2][4], rs[4];
#pragma unroll
    for (int q = 0; q < 4; ++q) {
      const float mnew = fmaxf(mrow[q], rm[q]);
      const float fac = __expf(mrow[q] - mnew);
      mrow[q] = mnew;
      lrow[q] *= fac;
#pragma unroll
      for (int hdb = 0; hdb < 4; ++hdb) acc[hdb][q] *= fac;
      p[0][q] = valid[0][q] ? __expf(sv[0][q] - mnew) : 0.f;
      p[1][q] = valid[1][q] ? __expf(sv[1][q] - mnew) : 0.f;
      rs[q] = p[0][q] + p[1][q];
    }
#pragma unroll
    for (int d = 1; d < 16; d <<= 1)
#pragma unroll
      for (int q = 0; q < 4; ++q) rs[q] += __shfl_xor(rs[q], d);
#pragma unroll
    for (int q = 0; q < 4; ++q) lrow[q] += rs[q];
#pragma unroll
    for (int f = 0; f < 2; ++f)
#pragma unroll
      for (int q = 0; q < 4; ++q)
        plds[w][(g * 4 + q) * 32 + f * 16 + r] = __float2bfloat16(p[f][q]);
    asm volatile("s_waitcnt lgkmcnt(0)" ::: "memory");
    __builtin_amdgcn_sched_barrier(0);
    const short8 pa = *(const short8*)&plds[w][r * 32 + g * 8];
#pragma unroll
    for (int hdb = 0; hdb < 4; ++hdb) {
      short8 vf = *(const short8*)&vp[(size_t)(hdb * 16 + r) * 2048 + kbase + g * 8];
      acc[hdb] = MFMA16(pa, vf, acc[hdb]);
    }
  }

  const int b_ = bh >> 4, h = bh & 15;
#pragma unroll
  for (int hdb = 0; hdb < 4; ++hdb)
#pragma unroll
    for (int q = 0; q < 4; ++q) {
      const int i_ = qa + g * 4 + q;
      yb[(size_t)(b_ * 2048 + i_) * 1024 + h * 64 + hdb * 16 + r] =
          __float2bfloat16(acc[hdb][q] / lrow[q]);
    }
}

// ---------------------------------------------------------------- launch
extern "C" void kernel_launch(void* const* d_in, const int* in_sizes, int n_in,
                              void* d_out, int out_size, void* d_ws,
                              size_t ws_size, hipStream_t stream) {
  const float* x = (const float*)d_in[0];
  const float* Wqkv = (const float*)d_in[1];
  const float* bqkv = (const float*)d_in[2];
  const float* Wo = (const float*)d_in[3];
  const float* bo = (const float*)d_in[4];
  float* out = (float*)d_out;

  char* ws = (char*)d_ws;
  __hip_bfloat16* xb = (__hip_bfloat16*)(ws + 0);                    // 8 MB
  __hip_bfloat16* wqkvb = (__hip_bfloat16*)(ws + 8388608);           // 6 MB
  __hip_bfloat16* wob = (__hip_bfloat16*)(ws + 14680064);            // 2 MB
  __hip_bfloat16* qb = (__hip_bfloat16*)(ws + 16777216);             // 8 MB
  __hip_bfloat16* kb = (__hip_bfloat16*)(ws + 25165824);             // 8 MB
  __hip_bfloat16* vt = (__hip_bfloat16*)(ws + 33554432);             // 8 MB
  __hip_bfloat16* yb = (__hip_bfloat16*)(ws + 41943040);             // 8 MB

  cvt_all<<<2048, 256, 0, stream>>>(x, Wqkv, Wo, xb, wqkvb, wob);

  // QKV: M=4096, N=3072, K=1024 -> 16x12 = 192 blocks of 256x256
  gemm256p<0><<<192, 512, 0, stream>>>(xb, wqkvb, bqkv, nullptr, qb, kb, vt,
                                       1024, 12);
  // attention: (B*H) * (T/64) = 32 * 32 blocks
  attn_local<<<1024, 256, 0, stream>>>(qb, kb, vt, yb);
  // out: M=4096, N=1024, K=1024 -> 32x8 = 256 blocks of 128x128
  gemm_bt_out<<<256, 256, 0, stream>>>(yb, wob, bo, out, 1024, 8);
}

// Round 4
// 110.182 us; speedup vs baseline: 1.1944x; 1.0584x over previous
//
#include <hip/hip_runtime.h>
#include <hip/hip_bf16.h>
#include <stdint.h>

// Problem constants: B=2, T=2048, D=1024, H=16, W=256, HD=64; M = B*T = 4096.

typedef __attribute__((ext_vector_type(8))) short short8;
typedef __attribute__((ext_vector_type(4))) float f32x4;

#define MFMA16(a, b, c) __builtin_amdgcn_mfma_f32_16x16x32_bf16((a), (b), (c), 0, 0, 0)

static __device__ __forceinline__ void gl_lds16(const void* g, void* l) {
  __builtin_amdgcn_global_load_lds(
      (const __attribute__((address_space(1))) unsigned int*)g,
      (__attribute__((address_space(3))) unsigned int*)l, 16, 0, 0);
}

#define LGKM0 do { asm volatile("s_waitcnt lgkmcnt(0)" ::: "memory"); \
                   __builtin_amdgcn_sched_barrier(0); } while (0)
#define BARM do { asm volatile("" ::: "memory"); \
                  __builtin_amdgcn_s_barrier(); \
                  asm volatile("" ::: "memory"); } while (0)

// ---------------------------------------------------------------- convert all
__global__ void cvt_all(const float* __restrict__ x, const float* __restrict__ wqkv,
                        const float* __restrict__ wo, __hip_bfloat16* __restrict__ xb,
                        __hip_bfloat16* __restrict__ wqkvb,
                        __hip_bfloat16* __restrict__ wob) {
  const int N0 = 524288, N1 = 393216, N2 = 131072;  // granules of 8 floats
  int i = blockIdx.x * blockDim.x + threadIdx.x;
  const int stride = gridDim.x * blockDim.x;
  for (; i < N0 + N1 + N2; i += stride) {
    const float* in;
    __hip_bfloat16* out;
    int gidx;
    if (i < N0) { in = x; out = xb; gidx = i; }
    else if (i < N0 + N1) { in = wqkv; out = wqkvb; gidx = i - N0; }
    else { in = wo; out = wob; gidx = i - N0 - N1; }
    const float4* p = (const float4*)in + (size_t)gidx * 2;
    float4 v0 = p[0], v1 = p[1];
    union { short8 s; __hip_bfloat16 h[8]; } u;
    u.h[0] = __float2bfloat16(v0.x); u.h[1] = __float2bfloat16(v0.y);
    u.h[2] = __float2bfloat16(v0.z); u.h[3] = __float2bfloat16(v0.w);
    u.h[4] = __float2bfloat16(v1.x); u.h[5] = __float2bfloat16(v1.y);
    u.h[6] = __float2bfloat16(v1.z); u.h[7] = __float2bfloat16(v1.w);
    ((short8*)out)[gidx] = u.s;
  }
}

// ---------------------------------------------------------------- QKV GEMM
// C[m][n] = sum_k A[m][k]*Bm[n][k] + bias[n], scattered to q/k/v.
// BM=256, BN=192, BK=64, 8 waves (2Mx4N), per-wave out 128x48.
// Grid 16x16 = 256 blocks = exact CU cover.
// LDS: 2 bufs x [A 32KB | B 24KB] = 112KB. Row = 128B (two 32-elem K planes
// inline), 16B slot swizzle: slot = (p*4+g) ^ ((row>>1)&7)  (<=2-way reads).
// Staged via global_load_lds, linear dest, inverse-swizzled global source.
// Stage unit = 64 rows (8KB) = 1 gl_lds/thread.  During tile t stage tile t+2
// (A at ph2, B at ph3 -- both after their regions' reads provably complete).
// One vmcnt(7) per tile (issue->wait ~5 phases).
__global__ __launch_bounds__(512) void gemm_qkv(
    const __hip_bfloat16* __restrict__ A, const __hip_bfloat16* __restrict__ Bm,
    const float* __restrict__ bias,
    __hip_bfloat16* __restrict__ qb, __hip_bfloat16* __restrict__ kb,
    __hip_bfloat16* __restrict__ vt) {
  __shared__ alignas(128) char smem[114688];
  const int tid = threadIdx.x;
  const int lane = tid & 63, w = tid >> 6;
  const int wm = w >> 2, wn = w & 3;
  const int r = lane & 15, g = lane >> 4;
  const int K = 1024, NT = 16;

  // XCD-aware swizzle over 256 blocks (bijective: 256 % 8 == 0)
  const int cpx = gridDim.x >> 3;
  const int swzb = (blockIdx.x & 7) * cpx + (blockIdx.x >> 3);
  const int bm = swzb >> 4, bn = swzb & 15;

  // ---- staging setup: unit = 64 rows x 128B; thread t -> row srow, slot tid&7
  const int srow = tid >> 3;
  const int e = (tid & 7) ^ ((tid >> 4) & 7);     // inverse of read swizzle
  const int koff = (e >> 2) * 32 + (e & 3) * 8;   // element offset in row
  const __hip_bfloat16* aU[4];
  const __hip_bfloat16* bU[3];
#pragma unroll
  for (int U = 0; U < 4; ++U)
    aU[U] = A + (size_t)(bm * 256 + U * 64 + srow) * K + koff;
#pragma unroll
  for (int U = 0; U < 3; ++U)
    bU[U] = Bm + (size_t)(bn * 192 + U * 64 + srow) * K + koff;
  const int ldst = tid * 16;

#define STA(t, U) gl_lds16(aU[U] + (t) * 64, smem + ((t) & 1) * 57344 + (U) * 8192 + ldst)
#define STB(t, U) gl_lds16(bU[U] + (t) * 64, smem + ((t) & 1) * 57344 + 32768 + (U) * 8192 + ldst)

  // ---- read setup
  const int hsw = (r >> 1) & 7;
  const int s0 = ((0 + g) ^ hsw) * 16;  // plane 0 slot byte
  const int s1 = ((4 + g) ^ hsw) * 16;  // plane 1 slot byte
  const int rdA = (wm * 128 + r) * 128;          // + buf + i*2048 + s{0,1}
  const int rdB = 32768 + (wn * 48 + r) * 128;   // + buf + j*2048 + s{0,1}

  f32x4 acc[8][3] = {};
  short8 a0[4][2], a1[4][2], bb[3][2];

  // ---- prologue: tiles 0 and 1
#pragma unroll
  for (int U = 0; U < 4; ++U) STA(0, U);
#pragma unroll
  for (int U = 0; U < 3; ++U) STB(0, U);
#pragma unroll
  for (int U = 0; U < 4; ++U) STA(1, U);
#pragma unroll
  for (int U = 0; U < 3; ++U) STB(1, U);
  asm volatile("s_waitcnt vmcnt(7)" ::: "memory");
  BARM;

#pragma unroll 1
  for (int t = 0; t < NT; ++t) {
    const char* cb = smem + (t & 1) * 57344;
    // ---- ph0: read a(i0-3) + b(j0-1); MFMA acc[0..3][0..1]
#pragma unroll
    for (int i = 0; i < 4; ++i) {
      a0[i][0] = *(const short8*)(cb + rdA + i * 2048 + s0);
      a0[i][1] = *(const short8*)(cb + rdA + i * 2048 + s1);
    }
#pragma unroll
    for (int j = 0; j < 2; ++j) {
      bb[j][0] = *(const short8*)(cb + rdB + j * 2048 + s0);
      bb[j][1] = *(const short8*)(cb + rdB + j * 2048 + s1);
    }
    BARM;
    LGKM0;
    __builtin_amdgcn_s_setprio(1);
#pragma unroll
    for (int i = 0; i < 4; ++i)
#pragma unroll
      for (int j = 0; j < 2; ++j) acc[i][j] = MFMA16(a0[i][0], bb[j][0], acc[i][j]);
#pragma unroll
    for (int i = 0; i < 4; ++i)
#pragma unroll
      for (int j = 0; j < 2; ++j) acc[i][j] = MFMA16(a0[i][1], bb[j][1], acc[i][j]);
    __builtin_amdgcn_s_setprio(0);
    BARM;
    // ---- ph1: read a(i4-7); MFMA acc[4..7][0..1]
#pragma unroll
    for (int i = 0; i < 4; ++i) {
      a1[i][0] = *(const short8*)(cb + rdA + (i + 4) * 2048 + s0);
      a1[i][1] = *(const short8*)(cb + rdA + (i + 4) * 2048 + s1);
    }
    BARM;
    LGKM0;
    __builtin_amdgcn_s_setprio(1);
#pragma unroll
    for (int i = 0; i < 4; ++i)
#pragma unroll
      for (int j = 0; j < 2; ++j) acc[i + 4][j] = MFMA16(a1[i][0], bb[j][0], acc[i + 4][j]);
#pragma unroll
    for (int i = 0; i < 4; ++i)
#pragma unroll
      for (int j = 0; j < 2; ++j) acc[i + 4][j] = MFMA16(a1[i][1], bb[j][1], acc[i + 4][j]);
    __builtin_amdgcn_s_setprio(0);
    BARM;
    // ---- ph2: read b(j2); stage A(t+2); MFMA acc[4..7][2]
    bb[2][0] = *(const short8*)(cb + rdB + 2 * 2048 + s0);
    bb[2][1] = *(const short8*)(cb + rdB + 2 * 2048 + s1);
    if (t + 2 < NT) {
      STA(t + 2, 0); STA(t + 2, 1); STA(t + 2, 2); STA(t + 2, 3);
    }
    BARM;
    LGKM0;
    __builtin_amdgcn_s_setprio(1);
#pragma unroll
    for (int i = 0; i < 4; ++i) acc[i + 4][2] = MFMA16(a1[i][0], bb[2][0], acc[i + 4][2]);
#pragma unroll
    for (int i = 0; i < 4; ++i) acc[i + 4][2] = MFMA16(a1[i][1], bb[2][1], acc[i + 4][2]);
    __builtin_amdgcn_s_setprio(0);
    BARM;
    // ---- ph3: stage B(t+2); MFMA acc[0..3][2]
    if (t + 2 < NT) {
      STB(t + 2, 0); STB(t + 2, 1); STB(t + 2, 2);
    }
    BARM;
    __builtin_amdgcn_s_setprio(1);
#pragma unroll
    for (int i = 0; i < 4; ++i) acc[i][2] = MFMA16(a0[i][0], bb[2][0], acc[i][2]);
#pragma unroll
    for (int i = 0; i < 4; ++i) acc[i][2] = MFMA16(a0[i][1], bb[2][1], acc[i][2]);
    __builtin_amdgcn_s_setprio(0);
    if (t + 2 < NT) {
      asm volatile("s_waitcnt vmcnt(7)" ::: "memory");
    } else if (t + 1 < NT) {
      asm volatile("s_waitcnt vmcnt(0)" ::: "memory");
    }
    BARM;
  }
#undef STA
#undef STB

  // ---- epilogue: scatter to q (scaled 1/8), k, v^T with bias
  float bjv[3];
  const int nb = bn * 192 + wn * 48;
#pragma unroll
  for (int j = 0; j < 3; ++j) bjv[j] = bias[nb + j * 16 + r];
#pragma unroll
  for (int i = 0; i < 8; ++i) {
    const int m0 = bm * 256 + wm * 128 + i * 16 + g * 4;
#pragma unroll
    for (int j = 0; j < 3; ++j) {
      const int nn = nb + j * 16 + r;
      const int c = nn >> 10, h = (nn >> 6) & 15, hd = nn & 63;
      const int b_ = m0 >> 11, t0 = m0 & 2047;
      const size_t hb = (size_t)(b_ * 16 + h);
      if (c == 0) {
#pragma unroll
        for (int q = 0; q < 4; ++q)
          qb[(hb * 2048 + t0 + q) * 64 + hd] =
              __float2bfloat16((acc[i][j][q] + bjv[j]) * 0.125f);
      } else if (c == 1) {
#pragma unroll
        for (int q = 0; q < 4; ++q)
          kb[(hb * 2048 + t0 + q) * 64 + hd] =
              __float2bfloat16(acc[i][j][q] + bjv[j]);
      } else {
        union { uint2 u; __hip_bfloat16 hh[4]; } pk;
#pragma unroll
        for (int q = 0; q < 4; ++q)
          pk.hh[q] = __float2bfloat16(acc[i][j][q] + bjv[j]);
        *(uint2*)&vt[(hb * 64 + hd) * 2048 + t0] = pk.u;
      }
    }
  }
}

// ---------------------------------------------------------------- 128x128 GEMM
// (out-projection: M=4096, N=1024 -> 256 blocks; proven correct)
__global__ __launch_bounds__(256) void gemm_bt_out(
    const __hip_bfloat16* __restrict__ A, const __hip_bfloat16* __restrict__ Bm,
    const float* __restrict__ bias, float* __restrict__ outF, int K, int nbn) {
  __shared__ alignas(16) __hip_bfloat16 As[128 * 32];
  __shared__ alignas(16) __hip_bfloat16 Bs[128 * 32];
  const int bm = blockIdx.x / nbn, bn = blockIdx.x % nbn;
  const int tid = threadIdx.x;
  const int lane = tid & 63, w = tid >> 6;
  const int wr = w >> 1, wc = w & 1;
  const int r = lane & 15, g = lane >> 4;

  f32x4 acc[4][4] = {};

  const int c0 = tid, c1 = tid + 256;
  const __hip_bfloat16* a0 = A + (size_t)(bm * 128 + (c0 >> 2)) * K + (c0 & 3) * 8;
  const __hip_bfloat16* a1 = A + (size_t)(bm * 128 + (c1 >> 2)) * K + (c1 & 3) * 8;
  const __hip_bfloat16* b0 = Bm + (size_t)(bn * 128 + (c0 >> 2)) * K + (c0 & 3) * 8;
  const __hip_bfloat16* b1 = Bm + (size_t)(bn * 128 + (c1 >> 2)) * K + (c1 & 3) * 8;
  __hip_bfloat16* la0 = &As[c0 * 8];
  __hip_bfloat16* la1 = &As[c1 * 8];
  __hip_bfloat16* lb0 = &Bs[c0 * 8];
  __hip_bfloat16* lb1 = &Bs[c1 * 8];

  for (int k0 = 0; k0 < K; k0 += 32) {
    gl_lds16(a0 + k0, la0);
    gl_lds16(a1 + k0, la1);
    gl_lds16(b0 + k0, lb0);
    gl_lds16(b1 + k0, lb1);
    __syncthreads();
    short8 af[4], bf[4];
#pragma unroll
    for (int i = 0; i < 4; ++i)
      af[i] = *(const short8*)&As[(wr * 64 + i * 16 + r) * 32 + g * 8];
#pragma unroll
    for (int j = 0; j < 4; ++j)
      bf[j] = *(const short8*)&Bs[(wc * 64 + j * 16 + r) * 32 + g * 8];
#pragma unroll
    for (int i = 0; i < 4; ++i)
#pragma unroll
      for (int j = 0; j < 4; ++j) acc[i][j] = MFMA16(af[i], bf[j], acc[i][j]);
    __syncthreads();
  }

#pragma unroll
  for (int i = 0; i < 4; ++i) {
    const int mbase = bm * 128 + wr * 64 + i * 16 + g * 4;
#pragma unroll
    for (int j = 0; j < 4; ++j) {
      const int nn = bn * 128 + wc * 64 + j * 16 + r;
      const float bv = bias[nn];
#pragma unroll
      for (int q = 0; q < 4; ++q)
        outF[(size_t)(mbase + q) * 1024 + nn] = acc[i][j][q] + bv;
    }
  }
}

// ---------------------------------------------------------------- attention
__global__ __launch_bounds__(256) void attn_local(
    const __hip_bfloat16* __restrict__ qb, const __hip_bfloat16* __restrict__ kb,
    const __hip_bfloat16* __restrict__ vt, __hip_bfloat16* __restrict__ yb) {
  __shared__ alignas(16) __hip_bfloat16 plds[4][16 * 32];
  const int bh = blockIdx.x >> 5;  // b*16 + h
  const int qt = blockIdx.x & 31;
  const int w = threadIdx.x >> 6, lane = threadIdx.x & 63;
  const int r = lane & 15, g = lane >> 4;
  const int qa = qt * 64 + w * 16;

  const __hip_bfloat16* qp = qb + (size_t)bh * 2048 * 64;
  const __hip_bfloat16* kp = kb + (size_t)bh * 2048 * 64;
  const __hip_bfloat16* vp = vt + (size_t)bh * 64 * 2048;

  const short8 qf0 = *(const short8*)&qp[(qa + r) * 64 + g * 8];
  const short8 qf1 = *(const short8*)&qp[(qa + r) * 64 + g * 8 + 32];

  f32x4 acc[4] = {};
  float mrow[4] = {-1e30f, -1e30f, -1e30f, -1e30f};
  float lrow[4] = {0.f, 0.f, 0.f, 0.f};

  const int jmin = qa > 255 ? qa - 255 : 0;
  const int kb_lo = jmin >> 5;
  const int kb_hi = (qa + 15) >> 5;

  for (int kbi = kb_lo; kbi <= kb_hi; ++kbi) {
    const int kbase = kbi << 5;
    f32x4 s[2] = {};
#pragma unroll
    for (int f = 0; f < 2; ++f) {
      short8 kf0 = *(const short8*)&kp[(kbase + f * 16 + r) * 64 + g * 8];
      short8 kf1 = *(const short8*)&kp[(kbase + f * 16 + r) * 64 + g * 8 + 32];
      s[f] = MFMA16(qf0, kf0, s[f]);
      s[f] = MFMA16(qf1, kf1, s[f]);
    }
    bool valid[2][4];
    float sv[2][4];
#pragma unroll
    for (int f = 0; f < 2; ++f)
#pragma unroll
      for (int q = 0; q < 4; ++q) {
        const int i_ = qa + g * 4 + q;
        const int j_ = kbase + f * 16 + r;
        valid[f][q] = (j_ <= i_) && (j_ + 255 >= i_);
        sv[f][q] = valid[f][q] ? s[f][q] : -1e30f;
      }
    float rm[4];
#pragma unroll
    for (int q = 0; q < 4; ++q) rm[q] = fmaxf(sv[0][q], sv[1][q]);
#pragma unroll
    for (int d = 1; d < 16; d <<= 1)
#pragma unroll
      for (int q = 0; q < 4; ++q) rm[q] = fmaxf(rm[q], __shfl_xor(rm[q], d));
    float p[2][4], rs[4];
#pragma unroll
    for (int q = 0; q < 4; ++q) {
      const float mnew = fmaxf(mrow[q], rm[q]);
      const float fac = __expf(mrow[q] - mnew);
      mrow[q] = mnew;
      lrow[q] *= fac;
#pragma unroll
      for (int hdb = 0; hdb < 4; ++hdb) acc[hdb][q] *= fac;
      p[0][q] = valid[0][q] ? __expf(sv[0][q] - mnew) : 0.f;
      p[1][q] = valid[1][q] ? __expf(sv[1][q] - mnew) : 0.f;
      rs[q] = p[0][q] + p[1][q];
    }
#pragma unroll
    for (int d = 1; d < 16; d <<= 1)
#pragma unroll
      for (int q = 0; q < 4; ++q) rs[q] += __shfl_xor(rs[q], d);
#pragma unroll
    for (int q = 0; q < 4; ++q) lrow[q] += rs[q];
#pragma unroll
    for (int f = 0; f < 2; ++f)
#pragma unroll
      for (int q = 0; q < 4; ++q)
        plds[w][(g * 4 + q) * 32 + f * 16 + r] = __float2bfloat16(p[f][q]);
    asm volatile("s_waitcnt lgkmcnt(0)" ::: "memory");
    __builtin_amdgcn_sched_barrier(0);
    const short8 pa = *(const short8*)&plds[w][r * 32 + g * 8];
#pragma unroll
    for (int hdb = 0; hdb < 4; ++hdb) {
      short8 vf = *(const short8*)&vp[(size_t)(hdb * 16 + r) * 2048 + kbase + g * 8];
      acc[hdb] = MFMA16(pa, vf, acc[hdb]);
    }
  }

  const int b_ = bh >> 4, h = bh & 15;
#pragma unroll
  for (int hdb = 0; hdb < 4; ++hdb)
#pragma unroll
    for (int q = 0; q < 4; ++q) {
      const int i_ = qa + g * 4 + q;
      yb[(size_t)(b_ * 2048 + i_) * 1024 + h * 64 + hdb * 16 + r] =
          __float2bfloat16(acc[hdb][q] / lrow[q]);
    }
}

// ---------------------------------------------------------------- launch
extern "C" void kernel_launch(void* const* d_in, const int* in_sizes, int n_in,
                              void* d_out, int out_size, void* d_ws,
                              size_t ws_size, hipStream_t stream) {
  const float* x = (const float*)d_in[0];
  const float* Wqkv = (const float*)d_in[1];
  const float* bqkv = (const float*)d_in[2];
  const float* Wo = (const float*)d_in[3];
  const float* bo = (const float*)d_in[4];
  float* out = (float*)d_out;

  char* ws = (char*)d_ws;
  __hip_bfloat16* xb = (__hip_bfloat16*)(ws + 0);                    // 8 MB
  __hip_bfloat16* wqkvb = (__hip_bfloat16*)(ws + 8388608);           // 6 MB
  __hip_bfloat16* wob = (__hip_bfloat16*)(ws + 14680064);            // 2 MB
  __hip_bfloat16* qb = (__hip_bfloat16*)(ws + 16777216);             // 8 MB
  __hip_bfloat16* kb = (__hip_bfloat16*)(ws + 25165824);             // 8 MB
  __hip_bfloat16* vt = (__hip_bfloat16*)(ws + 33554432);             // 8 MB
  __hip_bfloat16* yb = (__hip_bfloat16*)(ws + 41943040);             // 8 MB

  cvt_all<<<2048, 256, 0, stream>>>(x, Wqkv, Wo, xb, wqkvb, wob);

  // QKV: M=4096, N=3072, K=1024 -> 16x16 = 256 blocks of 256x192
  gemm_qkv<<<256, 512, 0, stream>>>(xb, wqkvb, bqkv, qb, kb, vt);
  // attention: (B*H) * (T/64) = 32 * 32 blocks
  attn_local<<<1024, 256, 0, stream>>>(qb, kb, vt, yb);
  // out: M=4096, N=1024, K=1024 -> 32x8 = 256 blocks of 128x128
  gemm_bt_out<<<256, 256, 0, stream>>>(yb, wob, bo, out, 1024, 8);
}

// Round 5
// 109.980 us; speedup vs baseline: 1.1966x; 1.0018x over previous
//
#include <hip/hip_runtime.h>
#include <hip/hip_bf16.h>
#include <stdint.h>

// Problem constants: B=2, T=2048, D=1024, H=16, W=256, HD=64; M = B*T = 4096.

typedef __attribute__((ext_vector_type(8))) short short8;
typedef __attribute__((ext_vector_type(4))) float f32x4;

#define MFMA16(a, b, c) __builtin_amdgcn_mfma_f32_16x16x32_bf16((a), (b), (c), 0, 0, 0)

static __device__ __forceinline__ void gl_lds16(const void* g, void* l) {
  __builtin_amdgcn_global_load_lds(
      (const __attribute__((address_space(1))) unsigned int*)g,
      (__attribute__((address_space(3))) unsigned int*)l, 16, 0, 0);
}

#define LGKM0 do { asm volatile("s_waitcnt lgkmcnt(0)" ::: "memory"); \
                   __builtin_amdgcn_sched_barrier(0); } while (0)
#define BARM do { asm volatile("" ::: "memory"); \
                  __builtin_amdgcn_s_barrier(); \
                  asm volatile("" ::: "memory"); } while (0)

// ---------------------------------------------------------------- convert all
__global__ void cvt_all(const float* __restrict__ x, const float* __restrict__ wqkv,
                        const float* __restrict__ wo, __hip_bfloat16* __restrict__ xb,
                        __hip_bfloat16* __restrict__ wqkvb,
                        __hip_bfloat16* __restrict__ wob) {
  const int N0 = 524288, N1 = 393216, N2 = 131072;  // granules of 8 floats
  int i = blockIdx.x * blockDim.x + threadIdx.x;
  const int stride = gridDim.x * blockDim.x;
  for (; i < N0 + N1 + N2; i += stride) {
    const float* in;
    __hip_bfloat16* out;
    int gidx;
    if (i < N0) { in = x; out = xb; gidx = i; }
    else if (i < N0 + N1) { in = wqkv; out = wqkvb; gidx = i - N0; }
    else { in = wo; out = wob; gidx = i - N0 - N1; }
    const float4* p = (const float4*)in + (size_t)gidx * 2;
    float4 v0 = p[0], v1 = p[1];
    union { short8 s; __hip_bfloat16 h[8]; } u;
    u.h[0] = __float2bfloat16(v0.x); u.h[1] = __float2bfloat16(v0.y);
    u.h[2] = __float2bfloat16(v0.z); u.h[3] = __float2bfloat16(v0.w);
    u.h[4] = __float2bfloat16(v1.x); u.h[5] = __float2bfloat16(v1.y);
    u.h[6] = __float2bfloat16(v1.z); u.h[7] = __float2bfloat16(v1.w);
    ((short8*)out)[gidx] = u.s;
  }
}

// ---------------------------------------------------------------- QKV GEMM
// (unchanged from round 3)
__global__ __launch_bounds__(512) void gemm_qkv(
    const __hip_bfloat16* __restrict__ A, const __hip_bfloat16* __restrict__ Bm,
    const float* __restrict__ bias,
    __hip_bfloat16* __restrict__ qb, __hip_bfloat16* __restrict__ kb,
    __hip_bfloat16* __restrict__ vt) {
  __shared__ alignas(128) char smem[114688];
  const int tid = threadIdx.x;
  const int lane = tid & 63, w = tid >> 6;
  const int wm = w >> 2, wn = w & 3;
  const int r = lane & 15, g = lane >> 4;
  const int K = 1024, NT = 16;

  const int cpx = gridDim.x >> 3;
  const int swzb = (blockIdx.x & 7) * cpx + (blockIdx.x >> 3);
  const int bm = swzb >> 4, bn = swzb & 15;

  const int srow = tid >> 3;
  const int e = (tid & 7) ^ ((tid >> 4) & 7);
  const int koff = (e >> 2) * 32 + (e & 3) * 8;
  const __hip_bfloat16* aU[4];
  const __hip_bfloat16* bU[3];
#pragma unroll
  for (int U = 0; U < 4; ++U)
    aU[U] = A + (size_t)(bm * 256 + U * 64 + srow) * K + koff;
#pragma unroll
  for (int U = 0; U < 3; ++U)
    bU[U] = Bm + (size_t)(bn * 192 + U * 64 + srow) * K + koff;
  const int ldst = tid * 16;

#define STA(t, U) gl_lds16(aU[U] + (t) * 64, smem + ((t) & 1) * 57344 + (U) * 8192 + ldst)
#define STB(t, U) gl_lds16(bU[U] + (t) * 64, smem + ((t) & 1) * 57344 + 32768 + (U) * 8192 + ldst)

  const int hsw = (r >> 1) & 7;
  const int s0 = ((0 + g) ^ hsw) * 16;
  const int s1 = ((4 + g) ^ hsw) * 16;
  const int rdA = (wm * 128 + r) * 128;
  const int rdB = 32768 + (wn * 48 + r) * 128;

  f32x4 acc[8][3] = {};
  short8 a0[4][2], a1[4][2], bb[3][2];

#pragma unroll
  for (int U = 0; U < 4; ++U) STA(0, U);
#pragma unroll
  for (int U = 0; U < 3; ++U) STB(0, U);
#pragma unroll
  for (int U = 0; U < 4; ++U) STA(1, U);
#pragma unroll
  for (int U = 0; U < 3; ++U) STB(1, U);
  asm volatile("s_waitcnt vmcnt(7)" ::: "memory");
  BARM;

#pragma unroll 1
  for (int t = 0; t < NT; ++t) {
    const char* cb = smem + (t & 1) * 57344;
#pragma unroll
    for (int i = 0; i < 4; ++i) {
      a0[i][0] = *(const short8*)(cb + rdA + i * 2048 + s0);
      a0[i][1] = *(const short8*)(cb + rdA + i * 2048 + s1);
    }
#pragma unroll
    for (int j = 0; j < 2; ++j) {
      bb[j][0] = *(const short8*)(cb + rdB + j * 2048 + s0);
      bb[j][1] = *(const short8*)(cb + rdB + j * 2048 + s1);
    }
    BARM;
    LGKM0;
    __builtin_amdgcn_s_setprio(1);
#pragma unroll
    for (int i = 0; i < 4; ++i)
#pragma unroll
      for (int j = 0; j < 2; ++j) acc[i][j] = MFMA16(a0[i][0], bb[j][0], acc[i][j]);
#pragma unroll
    for (int i = 0; i < 4; ++i)
#pragma unroll
      for (int j = 0; j < 2; ++j) acc[i][j] = MFMA16(a0[i][1], bb[j][1], acc[i][j]);
    __builtin_amdgcn_s_setprio(0);
    BARM;
#pragma unroll
    for (int i = 0; i < 4; ++i) {
      a1[i][0] = *(const short8*)(cb + rdA + (i + 4) * 2048 + s0);
      a1[i][1] = *(const short8*)(cb + rdA + (i + 4) * 2048 + s1);
    }
    BARM;
    LGKM0;
    __builtin_amdgcn_s_setprio(1);
#pragma unroll
    for (int i = 0; i < 4; ++i)
#pragma unroll
      for (int j = 0; j < 2; ++j) acc[i + 4][j] = MFMA16(a1[i][0], bb[j][0], acc[i + 4][j]);
#pragma unroll
    for (int i = 0; i < 4; ++i)
#pragma unroll
      for (int j = 0; j < 2; ++j) acc[i + 4][j] = MFMA16(a1[i][1], bb[j][1], acc[i + 4][j]);
    __builtin_amdgcn_s_setprio(0);
    BARM;
    bb[2][0] = *(const short8*)(cb + rdB + 2 * 2048 + s0);
    bb[2][1] = *(const short8*)(cb + rdB + 2 * 2048 + s1);
    if (t + 2 < NT) {
      STA(t + 2, 0); STA(t + 2, 1); STA(t + 2, 2); STA(t + 2, 3);
    }
    BARM;
    LGKM0;
    __builtin_amdgcn_s_setprio(1);
#pragma unroll
    for (int i = 0; i < 4; ++i) acc[i + 4][2] = MFMA16(a1[i][0], bb[2][0], acc[i + 4][2]);
#pragma unroll
    for (int i = 0; i < 4; ++i) acc[i + 4][2] = MFMA16(a1[i][1], bb[2][1], acc[i + 4][2]);
    __builtin_amdgcn_s_setprio(0);
    BARM;
    if (t + 2 < NT) {
      STB(t + 2, 0); STB(t + 2, 1); STB(t + 2, 2);
    }
    BARM;
    __builtin_amdgcn_s_setprio(1);
#pragma unroll
    for (int i = 0; i < 4; ++i) acc[i][2] = MFMA16(a0[i][0], bb[2][0], acc[i][2]);
#pragma unroll
    for (int i = 0; i < 4; ++i) acc[i][2] = MFMA16(a0[i][1], bb[2][1], acc[i][2]);
    __builtin_amdgcn_s_setprio(0);
    if (t + 2 < NT) {
      asm volatile("s_waitcnt vmcnt(7)" ::: "memory");
    } else if (t + 1 < NT) {
      asm volatile("s_waitcnt vmcnt(0)" ::: "memory");
    }
    BARM;
  }
#undef STA
#undef STB

  float bjv[3];
  const int nb = bn * 192 + wn * 48;
#pragma unroll
  for (int j = 0; j < 3; ++j) bjv[j] = bias[nb + j * 16 + r];
#pragma unroll
  for (int i = 0; i < 8; ++i) {
    const int m0 = bm * 256 + wm * 128 + i * 16 + g * 4;
#pragma unroll
    for (int j = 0; j < 3; ++j) {
      const int nn = nb + j * 16 + r;
      const int c = nn >> 10, h = (nn >> 6) & 15, hd = nn & 63;
      const int b_ = m0 >> 11, t0 = m0 & 2047;
      const size_t hb = (size_t)(b_ * 16 + h);
      if (c == 0) {
#pragma unroll
        for (int q = 0; q < 4; ++q)
          qb[(hb * 2048 + t0 + q) * 64 + hd] =
              __float2bfloat16((acc[i][j][q] + bjv[j]) * 0.125f);
      } else if (c == 1) {
#pragma unroll
        for (int q = 0; q < 4; ++q)
          kb[(hb * 2048 + t0 + q) * 64 + hd] =
              __float2bfloat16(acc[i][j][q] + bjv[j]);
      } else {
        union { uint2 u; __hip_bfloat16 hh[4]; } pk;
#pragma unroll
        for (int q = 0; q < 4; ++q)
          pk.hh[q] = __float2bfloat16(acc[i][j][q] + bjv[j]);
        *(uint2*)&vt[(hb * 64 + hd) * 2048 + t0] = pk.u;
      }
    }
  }
}

// ---------------------------------------------------------------- 128x128 GEMM
// (out-projection, unchanged)
__global__ __launch_bounds__(256) void gemm_bt_out(
    const __hip_bfloat16* __restrict__ A, const __hip_bfloat16* __restrict__ Bm,
    const float* __restrict__ bias, float* __restrict__ outF, int K, int nbn) {
  __shared__ alignas(16) __hip_bfloat16 As[128 * 32];
  __shared__ alignas(16) __hip_bfloat16 Bs[128 * 32];
  const int bm = blockIdx.x / nbn, bn = blockIdx.x % nbn;
  const int tid = threadIdx.x;
  const int lane = tid & 63, w = tid >> 6;
  const int wr = w >> 1, wc = w & 1;
  const int r = lane & 15, g = lane >> 4;

  f32x4 acc[4][4] = {};

  const int c0 = tid, c1 = tid + 256;
  const __hip_bfloat16* a0 = A + (size_t)(bm * 128 + (c0 >> 2)) * K + (c0 & 3) * 8;
  const __hip_bfloat16* a1 = A + (size_t)(bm * 128 + (c1 >> 2)) * K + (c1 & 3) * 8;
  const __hip_bfloat16* b0 = Bm + (size_t)(bn * 128 + (c0 >> 2)) * K + (c0 & 3) * 8;
  const __hip_bfloat16* b1 = Bm + (size_t)(bn * 128 + (c1 >> 2)) * K + (c1 & 3) * 8;
  __hip_bfloat16* la0 = &As[c0 * 8];
  __hip_bfloat16* la1 = &As[c1 * 8];
  __hip_bfloat16* lb0 = &Bs[c0 * 8];
  __hip_bfloat16* lb1 = &Bs[c1 * 8];

  for (int k0 = 0; k0 < K; k0 += 32) {
    gl_lds16(a0 + k0, la0);
    gl_lds16(a1 + k0, la1);
    gl_lds16(b0 + k0, lb0);
    gl_lds16(b1 + k0, lb1);
    __syncthreads();
    short8 af[4], bf[4];
#pragma unroll
    for (int i = 0; i < 4; ++i)
      af[i] = *(const short8*)&As[(wr * 64 + i * 16 + r) * 32 + g * 8];
#pragma unroll
    for (int j = 0; j < 4; ++j)
      bf[j] = *(const short8*)&Bs[(wc * 64 + j * 16 + r) * 32 + g * 8];
#pragma unroll
    for (int i = 0; i < 4; ++i)
#pragma unroll
      for (int j = 0; j < 4; ++j) acc[i][j] = MFMA16(af[i], bf[j], acc[i][j]);
    __syncthreads();
  }

#pragma unroll
  for (int i = 0; i < 4; ++i) {
    const int mbase = bm * 128 + wr * 64 + i * 16 + g * 4;
#pragma unroll
    for (int j = 0; j < 4; ++j) {
      const int nn = bn * 128 + wc * 64 + j * 16 + r;
      const float bv = bias[nn];
#pragma unroll
      for (int q = 0; q < 4; ++q)
        outF[(size_t)(mbase + q) * 1024 + nn] = acc[i][j][q] + bv;
    }
  }
}

// ---------------------------------------------------------------- attention v2
// Grid 512 = 8 XCD-pinned groups: head = (blk&7) + (slot>>4)*8, qt = slot&15.
// Each XCD's L2 holds its 4 heads' K+V (2 MB). 8 waves x 16 q-rows (q-tile 128).
// Per wave: [one low-partial block iff qa>=256] + mask-free middle + diag block.
// Defer-max: cheap wave-wide test replaces max-reduce+rescale in steady state;
// l is per-lane partial, reduced once after the loop.
__global__ __launch_bounds__(512) void attn_local(
    const __hip_bfloat16* __restrict__ qb, const __hip_bfloat16* __restrict__ kb,
    const __hip_bfloat16* __restrict__ vt, __hip_bfloat16* __restrict__ yb) {
  __shared__ alignas(16) __hip_bfloat16 plds[8][16 * 32];
  const int xcd = blockIdx.x & 7, slot = blockIdx.x >> 3;
  const int bh = xcd + (slot >> 4) * 8;  // b*16 + h
  const int qt = slot & 15;
  const int w = threadIdx.x >> 6, lane = threadIdx.x & 63;
  const int r = lane & 15, g = lane >> 4;
  const int qa = qt * 128 + w * 16;

  const __hip_bfloat16* qp = qb + (size_t)bh * 2048 * 64;
  const __hip_bfloat16* kp = kb + (size_t)bh * 2048 * 64;
  const __hip_bfloat16* vp = vt + (size_t)bh * 64 * 2048;

  const short8 qf0 = *(const short8*)&qp[(qa + r) * 64 + g * 8];
  const short8 qf1 = *(const short8*)&qp[(qa + r) * 64 + g * 8 + 32];

  f32x4 acc[4] = {};
  float mrow[4] = {-1e30f, -1e30f, -1e30f, -1e30f};
  float lsum[4] = {0.f, 0.f, 0.f, 0.f};

  const int kb_lo = (qa >= 256) ? ((qa - 255) >> 5) : 0;
  const int kb_hi = (qa + 15) >> 5;

  // MODE: 0 = no mask, 1 = low edge (j >= i-255), 2 = diagonal (j <= i)
#define PROC(kbase_, MODE_)                                                    \
  do {                                                                         \
    const int kbase = (kbase_);                                                \
    f32x4 s[2] = {};                                                           \
    _Pragma("unroll") for (int f = 0; f < 2; ++f) {                            \
      short8 kf0 = *(const short8*)&kp[(kbase + f * 16 + r) * 64 + g * 8];     \
      short8 kf1 = *(const short8*)&kp[(kbase + f * 16 + r) * 64 + g * 8 + 32];\
      s[f] = MFMA16(qf0, kf0, s[f]);                                           \
      s[f] = MFMA16(qf1, kf1, s[f]);                                           \
    }                                                                          \
    float sv[2][4];                                                            \
    _Pragma("unroll") for (int f = 0; f < 2; ++f)                              \
    _Pragma("unroll") for (int q = 0; q < 4; ++q) {                            \
      if (MODE_ == 0) { sv[f][q] = s[f][q]; }                                  \
      else if (MODE_ == 1) {                                                   \
        sv[f][q] = (kbase + f * 16 + r + 255 >= qa + g * 4 + q) ? s[f][q]      \
                                                                : -1e30f;      \
      } else {                                                                 \
        sv[f][q] = (kbase + f * 16 + r <= qa + g * 4 + q) ? s[f][q] : -1e30f;  \
      }                                                                        \
    }                                                                          \
    float tmax = fmaxf(fmaxf(fmaxf(sv[0][0], sv[0][1]),                        \
                             fmaxf(sv[0][2], sv[0][3])),                       \
                       fmaxf(fmaxf(sv[1][0], sv[1][1]),                        \
                             fmaxf(sv[1][2], sv[1][3])));                      \
    float mmin = fminf(fminf(mrow[0], mrow[1]), fminf(mrow[2], mrow[3]));      \
    if (!__all(tmax <= mmin + 8.f)) {                                          \
      float rm[4];                                                             \
      _Pragma("unroll") for (int q = 0; q < 4; ++q)                            \
        rm[q] = fmaxf(sv[0][q], sv[1][q]);                                     \
      _Pragma("unroll") for (int d = 1; d < 16; d <<= 1)                       \
      _Pragma("unroll") for (int q = 0; q < 4; ++q)                            \
        rm[q] = fmaxf(rm[q], __shfl_xor(rm[q], d));                            \
      _Pragma("unroll") for (int q = 0; q < 4; ++q) {                          \
        const float mnew = fmaxf(mrow[q], rm[q]);                              \
        const float fac = __expf(mrow[q] - mnew);                              \
        mrow[q] = mnew;                                                        \
        lsum[q] *= fac;                                                        \
        _Pragma("unroll") for (int hdb = 0; hdb < 4; ++hdb)                    \
          acc[hdb][q] *= fac;                                                  \
      }                                                                        \
    }                                                                          \
    float p[2][4];                                                             \
    _Pragma("unroll") for (int f = 0; f < 2; ++f)                              \
    _Pragma("unroll") for (int q = 0; q < 4; ++q)                              \
      p[f][q] = __expf(sv[f][q] - mrow[q]);                                    \
    _Pragma("unroll") for (int q = 0; q < 4; ++q)                              \
      lsum[q] += p[0][q] + p[1][q];                                            \
    _Pragma("unroll") for (int f = 0; f < 2; ++f)                              \
    _Pragma("unroll") for (int q = 0; q < 4; ++q)                              \
      plds[w][(g * 4 + q) * 32 + f * 16 + r] = __float2bfloat16(p[f][q]);      \
    asm volatile("s_waitcnt lgkmcnt(0)" ::: "memory");                         \
    __builtin_amdgcn_sched_barrier(0);                                         \
    const short8 pa = *(const short8*)&plds[w][r * 32 + g * 8];                \
    _Pragma("unroll") for (int hdb = 0; hdb < 4; ++hdb) {                      \
      short8 vf =                                                              \
          *(const short8*)&vp[(size_t)(hdb * 16 + r) * 2048 + kbase + g * 8];  \
      acc[hdb] = MFMA16(pa, vf, acc[hdb]);                                     \
    }                                                                          \
  } while (0)

  int t = kb_lo;
  if (qa >= 256) { PROC(t << 5, 1); ++t; }
#pragma unroll 1
  for (; t < kb_hi; ++t) PROC(t << 5, 0);
  PROC(kb_hi << 5, 2);
#undef PROC

  // final l reduction over the 16 key-lanes
#pragma unroll
  for (int d = 1; d < 16; d <<= 1)
#pragma unroll
    for (int q = 0; q < 4; ++q) lsum[q] += __shfl_xor(lsum[q], d);

  const int b_ = bh >> 4, h = bh & 15;
#pragma unroll
  for (int hdb = 0; hdb < 4; ++hdb)
#pragma unroll
    for (int q = 0; q < 4; ++q) {
      const int i_ = qa + g * 4 + q;
      yb[(size_t)(b_ * 2048 + i_) * 1024 + h * 64 + hdb * 16 + r] =
          __float2bfloat16(acc[hdb][q] / lsum[q]);
    }
}

// ---------------------------------------------------------------- launch
extern "C" void kernel_launch(void* const* d_in, const int* in_sizes, int n_in,
                              void* d_out, int out_size, void* d_ws,
                              size_t ws_size, hipStream_t stream) {
  const float* x = (const float*)d_in[0];
  const float* Wqkv = (const float*)d_in[1];
  const float* bqkv = (const float*)d_in[2];
  const float* Wo = (const float*)d_in[3];
  const float* bo = (const float*)d_in[4];
  float* out = (float*)d_out;

  char* ws = (char*)d_ws;
  __hip_bfloat16* xb = (__hip_bfloat16*)(ws + 0);                    // 8 MB
  __hip_bfloat16* wqkvb = (__hip_bfloat16*)(ws + 8388608);           // 6 MB
  __hip_bfloat16* wob = (__hip_bfloat16*)(ws + 14680064);            // 2 MB
  __hip_bfloat16* qb = (__hip_bfloat16*)(ws + 16777216);             // 8 MB
  __hip_bfloat16* kb = (__hip_bfloat16*)(ws + 25165824);             // 8 MB
  __hip_bfloat16* vt = (__hip_bfloat16*)(ws + 33554432);             // 8 MB
  __hip_bfloat16* yb = (__hip_bfloat16*)(ws + 41943040);             // 8 MB

  cvt_all<<<2048, 256, 0, stream>>>(x, Wqkv, Wo, xb, wqkvb, wob);

  // QKV: M=4096, N=3072, K=1024 -> 16x16 = 256 blocks of 256x192
  gemm_qkv<<<256, 512, 0, stream>>>(xb, wqkvb, bqkv, qb, kb, vt);
  // attention: 8 XCD groups x (4 heads x 16 q-tiles of 128)
  attn_local<<<512, 512, 0, stream>>>(qb, kb, vt, yb);
  // out: M=4096, N=1024, K=1024 -> 32x8 = 256 blocks of 128x128
  gemm_bt_out<<<256, 256, 0, stream>>>(yb, wob, bo, out, 1024, 8);
}